// Round 1
// baseline (68.486 us; speedup 1.0000x reference)
//
#include <hip/hip_runtime.h>

// Reference telescopes: kl_loss = mean(log_q_z_given_x) - mean(log_prior).
// log_qz / log_qz_product (the O(B^2*D) pairwise work) cancel exactly and
// never appear in the output tuple. dataset_size is unused.
//
// Per-element kl term (i,d):
//   lq - lp = -0.5*((z-mu)^2*exp(-lv) + lv + L2PI) + 0.5*(z^2*exp(-1) + 1 + L2PI)
//           = -0.5*((z-mu)^2*exp(-lv) + lv) + 0.5*(z^2*0.36787944 + 1)

#define B_SZ      2048
#define T_SZ      512
#define D_SZ      32
#define N_RECON4  (B_SZ * T_SZ / 4)   // 262144 float4
#define N_KL4     (B_SZ * D_SZ / 4)   // 16384 float4
#define NBLOCKS   256

__device__ __forceinline__ float kl_elem(float z, float m, float lv) {
    float t = z - m;
    return -0.5f * (t * t * __expf(-lv) + lv)
         + 0.5f * (z * z * 0.36787944117144233f + 1.0f);
}

__global__ __launch_bounds__(256) void tcvae_partial(
    const float* __restrict__ recon, const float* __restrict__ x,
    const float* __restrict__ mu, const float* __restrict__ lv,
    const float* __restrict__ z, float* __restrict__ partials)
{
    const int tid = blockIdx.x * blockDim.x + threadIdx.x;
    const int stride = gridDim.x * blockDim.x;

    float racc = 0.0f, kacc = 0.0f;

    const float4* x4 = (const float4*)x;
    const float4* r4 = (const float4*)recon;
    for (int i = tid; i < N_RECON4; i += stride) {
        float4 a = x4[i], b = r4[i];
        racc += fabsf(a.x - b.x) + fabsf(a.y - b.y)
              + fabsf(a.z - b.z) + fabsf(a.w - b.w);
    }

    const float4* z4 = (const float4*)z;
    const float4* m4 = (const float4*)mu;
    const float4* l4 = (const float4*)lv;
    for (int i = tid; i < N_KL4; i += stride) {
        float4 zz = z4[i], mm = m4[i], ll = l4[i];
        kacc += kl_elem(zz.x, mm.x, ll.x) + kl_elem(zz.y, mm.y, ll.y)
              + kl_elem(zz.z, mm.z, ll.z) + kl_elem(zz.w, mm.w, ll.w);
    }

    // wave (64-lane) reduction
    #pragma unroll
    for (int off = 32; off > 0; off >>= 1) {
        racc += __shfl_down(racc, off, 64);
        kacc += __shfl_down(kacc, off, 64);
    }

    __shared__ float sr[4], sk[4];
    const int lane = threadIdx.x & 63;
    const int wid  = threadIdx.x >> 6;
    if (lane == 0) { sr[wid] = racc; sk[wid] = kacc; }
    __syncthreads();
    if (threadIdx.x == 0) {
        partials[blockIdx.x]           = sr[0] + sr[1] + sr[2] + sr[3];
        partials[NBLOCKS + blockIdx.x] = sk[0] + sk[1] + sk[2] + sk[3];
    }
}

__global__ __launch_bounds__(256) void tcvae_final(
    const float* __restrict__ partials, float* __restrict__ out)
{
    float racc = 0.0f, kacc = 0.0f;
    for (int i = threadIdx.x; i < NBLOCKS; i += 256) {
        racc += partials[i];
        kacc += partials[NBLOCKS + i];
    }

    #pragma unroll
    for (int off = 32; off > 0; off >>= 1) {
        racc += __shfl_down(racc, off, 64);
        kacc += __shfl_down(kacc, off, 64);
    }

    __shared__ float sr[4], sk[4];
    const int lane = threadIdx.x & 63;
    const int wid  = threadIdx.x >> 6;
    if (lane == 0) { sr[wid] = racc; sk[wid] = kacc; }
    __syncthreads();
    if (threadIdx.x == 0) {
        float r = (sr[0] + sr[1] + sr[2] + sr[3]) * (1.0f / (float)(B_SZ * T_SZ));
        float k = (sk[0] + sk[1] + sk[2] + sk[3]) * (1.0f / (float)B_SZ);
        out[0] = r + k;   // total_loss
        out[1] = r;       // recon_loss
        out[2] = k;       // kl_loss
    }
}

extern "C" void kernel_launch(void* const* d_in, const int* in_sizes, int n_in,
                              void* d_out, int out_size, void* d_ws, size_t ws_size,
                              hipStream_t stream) {
    const float* recon = (const float*)d_in[0];
    const float* x     = (const float*)d_in[1];
    const float* mu    = (const float*)d_in[2];
    const float* lv    = (const float*)d_in[3];
    const float* z     = (const float*)d_in[4];
    // d_in[5] (dataset_size) is algebraically unused in the outputs.

    float* partials = (float*)d_ws;        // 2 * NBLOCKS floats
    float* out      = (float*)d_out;       // 3 floats

    tcvae_partial<<<NBLOCKS, 256, 0, stream>>>(recon, x, mu, lv, z, partials);
    tcvae_final<<<1, 256, 0, stream>>>(partials, out);
}